// Round 8
// baseline (552.472 us; speedup 1.0000x reference)
//
#include <hip/hip_runtime.h>
#include <hip/hip_bf16.h>

// Submanifold sparse conv 3x3x3, G=128, Cin=Cout=32.
// R8: spatial counting-sort for gather locality.
//  1. hist: count points per 16^3 cell (512 cells, octant-major key)
//  2. scan: exclusive prefix (Hillis-Steele in LDS) -> cursors + octant offsets
//  3. scatter: sortpos p via atomicAdd(cursor); orig[p]=i; posS[p]=pos[i];
//     feats row i -> bf16 -> featsB[p] (permuted); 64-bit table entry
//     atomicMax((origid<<20|p)+1)  [max origid = numpy last-write-wins];
//     + wt -> bf16 fragment-order wtT.
//  4. conv: blockIdx%8 = octant (XCD round-robin heuristic); waves process
//     16-point tiles of sorted points; 27 table lookups (MLP), bf16 row
//     gathers (sorted -> L2-local), LDS weights conflict-free, 2 MFMAs/k;
//     out written via orig[] permutation.

#define GRID 128
#define CIN 32
#define COUT 32
#define NOFF 27
#define NCELL 512

typedef __attribute__((ext_vector_type(8))) short bf16x8;
typedef __attribute__((ext_vector_type(4))) float f32x4;

__device__ inline unsigned short f2bf(float x) {
    union { float f; unsigned u; } v; v.f = x;
    unsigned r = v.u + 0x7fff + ((v.u >> 16) & 1);   // RTNE
    return (unsigned short)(r >> 16);
}

__device__ inline int cellkey(int x, int y, int z) {
    int cx = x >> 4, cy = y >> 4, cz = z >> 4;            // 8x8x8 cells
    int o = ((cx >> 2) << 2) | ((cy >> 2) << 1) | (cz >> 2);   // octant 0..7
    int w = ((cx & 3) << 4) | ((cy & 3) << 2) | (cz & 3);      // 0..63
    return (o << 6) | w;
}

__global__ void hist_kernel(const int* __restrict__ pos, int* __restrict__ hist, int N) {
    int i = blockIdx.x * 256 + threadIdx.x;
    if (i < N)
        atomicAdd(&hist[cellkey(pos[3 * i], pos[3 * i + 1], pos[3 * i + 2])], 1);
}

__global__ void scan_kernel(const int* __restrict__ hist,
                            int* __restrict__ cursor, int* __restrict__ off8) {
    __shared__ int s[NCELL];
    int t = threadIdx.x;
    s[t] = hist[t];
    __syncthreads();
    for (int d = 1; d < NCELL; d <<= 1) {
        int v = (t >= d) ? s[t - d] : 0;
        __syncthreads();
        s[t] += v;
        __syncthreads();
    }
    cursor[t] = (t == 0) ? 0 : s[t - 1];          // exclusive prefix
    if (t < 8) off8[t] = (t == 0) ? 0 : s[t * 64 - 1];
    if (t == 0) off8[8] = s[NCELL - 1];           // == N
}

__global__ void scatter_kernel(const float* __restrict__ feats,
                               const int* __restrict__ pos,
                               const float* __restrict__ wt,
                               int* __restrict__ cursor,
                               unsigned long long* __restrict__ tableS,
                               int* __restrict__ orig,
                               int* __restrict__ posS,
                               unsigned short* __restrict__ featsB,
                               unsigned short* __restrict__ wtT, int N) {
    int i = blockIdx.x * 256 + threadIdx.x;
    if (i < N) {
        int x = pos[3 * i], y = pos[3 * i + 1], z = pos[3 * i + 2];
        int p = atomicAdd(&cursor[cellkey(x, y, z)], 1);
        orig[p] = i;
        posS[3 * p] = x; posS[3 * p + 1] = y; posS[3 * p + 2] = z;
        // packed: high bits = orig id (duplicate winner = max orig id, numpy
        // last-write); low 20 bits = sorted pos; +1 so 0 means empty.
        unsigned long long packed =
            (((unsigned long long)i << 20) | (unsigned)p) + 1ULL;
        atomicMax(&tableS[(x * GRID + y) * GRID + z], packed);
        // feats row i -> bf16 -> featsB row p
        const float4* fr = (const float4*)(feats + (size_t)i * CIN);
        unsigned o16[8];
#pragma unroll
        for (int q = 0; q < 4; ++q) {
            float4 a = fr[2 * q], b = fr[2 * q + 1];
            o16[2 * q]     = (unsigned)f2bf(a.x) | ((unsigned)f2bf(a.y) << 16);
            // pack 4 floats -> 2 uints per float4
            o16[2 * q] = (unsigned)f2bf(a.x) | ((unsigned)f2bf(a.y) << 16);
            o16[2 * q + 1] = (unsigned)f2bf(a.z) | ((unsigned)f2bf(a.w) << 16);
            // b handled below
            (void)b;
        }
        // redo cleanly: 8 float4 -> 16 uints
        unsigned outw[16];
#pragma unroll
        for (int q = 0; q < 8; ++q) {
            float4 a = fr[q];
            outw[2 * q]     = (unsigned)f2bf(a.x) | ((unsigned)f2bf(a.y) << 16);
            outw[2 * q + 1] = (unsigned)f2bf(a.z) | ((unsigned)f2bf(a.w) << 16);
        }
        uint4* dst = (uint4*)(featsB + (size_t)p * CIN);
#pragma unroll
        for (int q = 0; q < 4; ++q) {
            uint4 v; v.x = outw[4 * q]; v.y = outw[4 * q + 1];
            v.z = outw[4 * q + 2]; v.w = outw[4 * q + 3];
            dst[q] = v;
        }
    }
    if (i < NOFF * CIN * COUT) {
        // wt [27][ci][co] -> bf16 fragment order:
        // idx = k*1024 + (co>>4)*512 + (ci>>3)*128 + (co&15)*8 + (ci&7)
        int k = i >> 10, r = i & 1023, ci = r >> 5, co = r & 31;
        int idx = k * 1024 + (co >> 4) * 512 + (ci >> 3) * 128 + (co & 15) * 8 + (ci & 7);
        wtT[idx] = f2bf(wt[i]);
    }
}

__global__ __launch_bounds__(1024, 8)
void conv_kernel(const unsigned short* __restrict__ featsB,
                 const int* __restrict__ posS,
                 const unsigned short* __restrict__ wtT,
                 const unsigned long long* __restrict__ tableS,
                 const int* __restrict__ orig,
                 const int* __restrict__ off8,
                 float* __restrict__ out, int N, int R) {
    __shared__ __align__(16) unsigned short ldsw[NOFF * 1024]; // 55296 B

    int tid = threadIdx.x;
    int wave = tid >> 6, lane = tid & 63;
    int m = lane & 15, quad = lane >> 4;

    // Stage W^T into LDS (fragment order -> contiguous copy, conflict-free).
    {
        const uint4* src = (const uint4*)wtT;    // 3456 x 16B
        uint4* dst = (uint4*)ldsw;
        for (int e = tid; e < NOFF * 1024 * 2 / 16; e += 1024)
            dst[e] = src[e];
    }
    __syncthreads();

    int o = blockIdx.x & 7;           // octant -> XCD (round-robin heuristic)
    int r = blockIdx.x >> 3;
    int lo = off8[o], hi = off8[o + 1];
    const unsigned short* wb = ldsw + (quad * 16 + m) * 8;

    for (int start = lo + r * 256; start < hi; start += R * 256) {
        int base = start + wave * 16;
        if (base >= hi) continue;      // wave-uniform; no syncthreads below

        int g = base + m;
        bool gv = g < N;
        int x = 0, y = 0, z = 0;
        if (gv) { x = posS[3 * g]; y = posS[3 * g + 1]; z = posS[3 * g + 2]; }
        int h = (x * GRID + y) * GRID + z;
        bool v0[3] = {gv && x > 0, gv, gv && x < GRID - 1};
        bool v1[3] = {gv && y > 0, gv, gv && y < GRID - 1};
        bool v2[3] = {gv && z > 0, gv, gv && z < GRID - 1};

        // 27 independent table lookups (MLP)
        int ids[NOFF];
#pragma unroll
        for (int k = 0; k < NOFF; ++k) {
            const int dx = k / 9, dy = (k / 3) % 3, dz = k % 3;   // 0..2
            bool ok = v0[dx] && v1[dy] && v2[dz];
            int hk = h + (dx - 1) * GRID * GRID + (dy - 1) * GRID + (dz - 1);
            hk = ok ? hk : 0;
            unsigned long long e = tableS[hk];
            ids[k] = (ok && e != 0ULL) ? (int)((e - 1ULL) & 0xFFFFFULL) : -1;
        }

        f32x4 acc0 = {0.f, 0.f, 0.f, 0.f};
        f32x4 acc1 = {0.f, 0.f, 0.f, 0.f};
#pragma unroll
        for (int k = 0; k < NOFF; ++k) {
            int id = ids[k];
            int row = (id >= 0 ? id : 0) * CIN;
            bf16x8 a = *(const bf16x8*)(featsB + (size_t)row + quad * 8);
            if (id < 0) a = (bf16x8){0, 0, 0, 0, 0, 0, 0, 0};

            bf16x8 b0 = *(const bf16x8*)(wb + k * 1024);        // co = m
            bf16x8 b1 = *(const bf16x8*)(wb + k * 1024 + 512);  // co = m+16

            acc0 = __builtin_amdgcn_mfma_f32_16x16x32_bf16(a, b0, acc0, 0, 0, 0);
            acc1 = __builtin_amdgcn_mfma_f32_16x16x32_bf16(a, b1, acc1, 0, 0, 0);
        }

        // D layout: col = lane&15 = co, row = quad*4+i = sorted point in tile
#pragma unroll
        for (int i2 = 0; i2 < 4; ++i2) {
            int ps = base + quad * 4 + i2;
            if (ps < N) {
                int og = orig[ps];
                out[(size_t)og * COUT + m]      = acc0[i2];
                out[(size_t)og * COUT + m + 16] = acc1[i2];
            }
        }
    }
}

extern "C" void kernel_launch(void* const* d_in, const int* in_sizes, int n_in,
                              void* d_out, int out_size, void* d_ws, size_t ws_size,
                              hipStream_t stream) {
    const float* feats = (const float*)d_in[0];   // [N, 32]
    const int*   pos   = (const int*)d_in[1];     // [N, 3]
    const float* wt    = (const float*)d_in[2];   // [27, 32, 32]
    float* out = (float*)d_out;                   // [N, 32]
    int N = in_sizes[0] / CIN;

    char* ws = (char*)d_ws;
    size_t off = 0;
    unsigned long long* tableS = (unsigned long long*)(ws + off);
    off += (size_t)GRID * GRID * GRID * 8;                 // 16 MB
    unsigned short* featsB = (unsigned short*)(ws + off);
    off += (size_t)N * CIN * 2;                            // 32 MB
    int* posS = (int*)(ws + off);   off += (size_t)N * 3 * 4;   // 6 MB
    int* orig = (int*)(ws + off);   off += (size_t)N * 4;       // 2 MB
    unsigned short* wtT = (unsigned short*)(ws + off);
    off += NOFF * CIN * COUT * 2;   off = (off + 255) & ~(size_t)255;
    int* hist = (int*)(ws + off);   off += NCELL * 4;
    int* cursor = (int*)(ws + off); off += NCELL * 4;
    int* off8 = (int*)(ws + off);   off += 16 * 4;

    hipMemsetAsync(tableS, 0, (size_t)GRID * GRID * GRID * 8, stream);
    hipMemsetAsync(hist, 0, NCELL * 4, stream);

    int nb = (N + 255) / 256;
    hist_kernel<<<nb, 256, 0, stream>>>(pos, hist, N);
    scan_kernel<<<1, NCELL, 0, stream>>>(hist, cursor, off8);
    scatter_kernel<<<nb, 256, 0, stream>>>(feats, pos, wt, cursor, tableS,
                                           orig, posS, featsB, wtT, N);

    int perOct = (N + 7) / 8;
    int R = (perOct + 255) / 256 + 2;     // + slack; while-loop covers overflow
    conv_kernel<<<8 * R, 1024, 0, stream>>>(featsB, posS, wtT, tableS, orig,
                                            off8, out, N, R);
}